// Round 9
// baseline (284.550 us; speedup 1.0000x reference)
//
#include <hip/hip_runtime.h>
#include <math.h>

#define N 3072
#define FEAT 128
#define NE 24576
#define PSTRIDE 64         // per-node pair-slot row stride
#define DOTB 768           // dot blocks (4 nodes each)
#define EDGB 96            // edge blocks (256 edges each)
#define OUTZ4 2458368      // f4 count of [Xnew|Anew|new_batch]
#define OZB 2401           // d_out zero blocks (1024 f4 each, bounds-checked)
#define GATB 192           // gather blocks in k_pgr
#define K2B (1 + GATB)     // 193 blocks, all co-resident (cap ~512)
#define RWAVES (K2B * 16)  // 3088 reduce waves

#define FOR24(M)  M(0)M(1)M(2)M(3)M(4)M(5)M(6)M(7)M(8)M(9)M(10)M(11)M(12)M(13)M(14)M(15)M(16)M(17)M(18)M(19)M(20)M(21)M(22)M(23)
#define FOR24R(M) M(23)M(22)M(21)M(20)M(19)M(18)M(17)M(16)M(15)M(14)M(13)M(12)M(11)M(10)M(9)M(8)M(7)M(6)M(5)M(4)M(3)M(2)M(1)M(0)

// Wave-aggregated atomic add: one atomicAdd per distinct key per wave.
__device__ __forceinline__ void wave_agg_add(bool valid, int key, float val,
                                             float* base, int stride, int off) {
    int lane = threadIdx.x & 63;
    unsigned long long active = __ballot(valid ? 1 : 0);
    while (active) {
        int leader = __ffsll(active) - 1;
        int lkey = __shfl(key, leader);
        bool mine = valid && (key == lkey);
        unsigned long long grp = __ballot(mine ? 1 : 0);
        float v = mine ? val : 0.0f;
        #pragma unroll
        for (int o = 32; o; o >>= 1) v += __shfl_xor(v, o);
        if (lane == leader)
            atomicAdd(&base[(size_t)lkey * stride + off], v);
        active &= ~grp;
    }
}

__device__ __forceinline__ int ctrl_ld(const int* p) {
    return __hip_atomic_load(p, __ATOMIC_RELAXED, __HIP_MEMORY_SCOPE_AGENT);
}

// blocks [0,DOTB): (first 6 also zero pcnt/notsing) dots a[i],c[i]; signal ctrl[0]
// blocks [DOTB,+EDGB): spin for dots, then score 256 edges each
// blocks [DOTB+EDGB,+OZB): zero [Xnew|Anew|new_batch]
__global__ void k_initez(const float* __restrict__ x, const float* __restrict__ w,
                         const int* __restrict__ ei, const float* __restrict__ bb,
                         float* __restrict__ a, float* __restrict__ c,
                         unsigned* __restrict__ ep, int* __restrict__ notsingle,
                         int* __restrict__ pcnt, unsigned long long* __restrict__ ptab,
                         float4* __restrict__ zout, float4* __restrict__ zws,
                         int* __restrict__ ctrl) {
    int b = blockIdx.x, t = threadIdx.x;
    if (b < DOTB) {
        float4 z = {0.f, 0.f, 0.f, 0.f};
        if (b < 6) zws[b * 256 + t] = z;          // [pcnt|notsing] = 1536 f4
        int node = b * 4 + (t >> 6);
        int lane = t & 63;
        const float* xi = x + node * FEAT;
        float pa = xi[lane] * w[lane] + xi[lane + 64] * w[lane + 64];
        float pc = xi[lane] * w[FEAT + lane] + xi[lane + 64] * w[FEAT + lane + 64];
        for (int off = 32; off; off >>= 1) {
            pa += __shfl_down(pa, off);
            pc += __shfl_down(pc, off);
        }
        if (lane == 0) { a[node] = pa; c[node] = pc; }
        __syncthreads();
        __threadfence();
        if (t == 0) atomicAdd(&ctrl[0], 1);
    } else if (b < DOTB + EDGB) {
        if (t == 0)
            while (ctrl_ld(&ctrl[0]) < DOTB) __builtin_amdgcn_s_sleep(2);
        __syncthreads();
        __threadfence();
        int s = (b - DOTB) * 256 + t;     // < NE
        int u = ei[s], v = ei[NE + s];
        unsigned wpk = (unsigned)u | ((unsigned)v << 12);
        if (u != v) {
            float bias = bb[0];
            float su = a[u] + c[v] + bias;   // S[u,v]; A_c[u,v]
            float sv = a[v] + c[u] + bias;   // S[v,u]; A_c[v,u]
            unsigned fu = (su > 0.f) ? 1u : 0u;
            unsigned fv = (sv > 0.f) ? 1u : 0u;
            wpk |= (fu << 24) | (fv << 25);
            if (fu | fv) { notsingle[u] = 1; notsingle[v] = 1; }
            float eu = tanhf(su);
            int sl = atomicAdd(&pcnt[v], 1);
            if (sl < PSTRIDE)
                ptab[(size_t)v * PSTRIDE + sl] =
                    ((unsigned long long)__float_as_uint(eu) << 32) | (unsigned)u;
            float ev2 = tanhf(sv);
            sl = atomicAdd(&pcnt[u], 1);
            if (sl < PSTRIDE)
                ptab[(size_t)u * PSTRIDE + sl] =
                    ((unsigned long long)__float_as_uint(ev2) << 32) | (unsigned)v;
        }
        ep[s] = wpk;
    } else {
        float4 z = {0.f, 0.f, 0.f, 0.f};
        int base = (b - DOTB - EDGB) * 1024;
        #pragma unroll
        for (int k = 0; k < 4; ++k) {
            int idx = base + k * 256 + t;
            if (idx < OUTZ4) zout[idx] = z;
        }
    }
}

// block 0: LDS fixpoint (edge cache in 24 NAMED registers, fwd+rev relax,
//          terminal-0 pruning) + rank + cluster; signals ctrl[2].
// blocks 1..GATB: dedup + gather y rows; signal ctrl[1].
// all blocks then: spin(gdone==GATB && cready) -> X-reduce + A-count.
__global__ void __launch_bounds__(1024)
k_pgr(const unsigned* __restrict__ ep, const float* __restrict__ x,
      const int* __restrict__ pcnt, const unsigned long long* __restrict__ ptab,
      const int* __restrict__ notsingle, float* __restrict__ y,
      unsigned long long* __restrict__ qmask, int* __restrict__ cluster,
      float* __restrict__ out_cluster, float* __restrict__ Xnew,
      float* __restrict__ Anew, int* __restrict__ ctrl) {
    __shared__ int lab[N];
    __shared__ int ssum[1024];
    __shared__ unsigned short rk[N];
    __shared__ int sh_p[16 * 64];
    __shared__ int flag;
    int t = threadIdx.x, blk = blockIdx.x;
    int wv = t >> 6, lane = t & 63;
    if (blk == 0) {
        unsigned act = 0;
        #define LDE(j) unsigned e##j = ep[t + (j) * 1024]; \
                       if (e##j & 0x3000000u) act |= (1u << (j));
        FOR24(LDE)
        for (int i = t; i < N; i += 1024) lab[i] = i;
        for (;;) {
            __syncthreads();
            if (t == 0) flag = 0;
            __syncthreads();
            #define RLX(j) if (act & (1u << (j))) { \
                int u_ = (int)(e##j & 0xFFFu); \
                int v_ = (int)((e##j >> 12) & 0xFFFu); \
                int lu_ = lab[u_], lv_ = lab[v_]; \
                if ((lu_ | lv_) == 0) { act &= ~(1u << (j)); } \
                else { \
                    if ((e##j & (1u << 24)) && lv_ < lu_) { atomicMin(&lab[u_], lv_); flag = 1; } \
                    if ((e##j & (1u << 25)) && lu_ < lv_) { atomicMin(&lab[v_], lu_); flag = 1; } \
                } }
            FOR24(RLX)
            FOR24R(RLX)
            for (int i = t; i < N; i += 1024) {
                int m = lab[i];
                if (m == 0) continue;
                int mm = lab[m];
                while (mm < m) { m = mm; mm = lab[m]; }
                if (m < lab[i]) { atomicMin(&lab[i], m); flag = 1; }
            }
            __syncthreads();
            if (!flag) break;
        }
        // rank roots: cumsum(lab[i]==i)-1; cluster[j]=rank[lab[j]]
        int i0 = 3 * t;
        int r0 = (lab[i0] == i0);
        int r1 = (lab[i0 + 1] == i0 + 1);
        int r2 = (lab[i0 + 2] == i0 + 2);
        int s = r0 + r1 + r2;
        ssum[t] = s;
        __syncthreads();
        for (int off = 1; off < 1024; off <<= 1) {
            int val = (t >= off) ? ssum[t - off] : 0;
            __syncthreads();
            ssum[t] += val;
            __syncthreads();
        }
        int run = ssum[t] - s;
        run += r0; rk[i0]     = (unsigned short)(run - 1);
        run += r1; rk[i0 + 1] = (unsigned short)(run - 1);
        run += r2; rk[i0 + 2] = (unsigned short)(run - 1);
        __syncthreads();
        for (int j = t; j < N; j += 1024) {
            int cl = rk[lab[j]];
            cluster[j] = cl;
            out_cluster[j] = (float)cl;
        }
        __syncthreads();
        __threadfence();
        if (t == 0) atomicAdd(&ctrl[2], 1);
    } else {
        int q = (blk - 1) * 16 + wv;
        int cnt = pcnt[q]; if (cnt > PSTRIDE) cnt = PSTRIDE;
        const unsigned long long* row = ptab + (size_t)q * PSTRIDE;
        int myp = -1 - lane;      // unique negative: never matches a real p
        float mye = 0.f;
        if (lane < cnt) {
            unsigned long long s = row[lane];
            myp = (int)(s & 0xFFFFFFFFu);
            mye = __uint_as_float((unsigned)(s >> 32));
        }
        sh_p[wv * 64 + lane] = myp;
        bool dup = false;
        for (int j = 0; j < lane && !dup; ++j)
            dup = (sh_p[wv * 64 + j] == myp);
        bool valid = (lane < cnt) && !dup;
        unsigned long long m = __ballot(valid ? 1 : 0);
        if (lane == 0) qmask[q] = m;
        float acc0 = 0.f, acc1 = 0.f;
        for (int j = 0; j < cnt; ++j) {
            if (!((m >> j) & 1ull)) continue;
            int p = __shfl(myp, j);
            float e = __shfl(mye, j);
            const float* xp = x + p * FEAT;
            acc0 += e * xp[lane];
            acc1 += e * xp[lane + 64];
        }
        if (!notsingle[q]) {
            const float* xq = x + q * FEAT;
            acc0 += xq[lane];
            acc1 += xq[lane + 64];
        }
        float* yq = y + q * FEAT;
        yq[lane] = acc0;
        yq[lane + 64] = acc1;
        __syncthreads();
        __threadfence();
        if (t == 0) atomicAdd(&ctrl[1], 1);
    }
    // ---- reduce phase: wait for all y rows + cluster ----
    if (t == 0) {
        while (ctrl_ld(&ctrl[1]) < GATB) __builtin_amdgcn_s_sleep(2);
        while (ctrl_ld(&ctrl[2]) < 1)    __builtin_amdgcn_s_sleep(2);
    }
    __syncthreads();
    __threadfence();
    for (int gw = blk * 16 + wv; gw < 9216; gw += RWAVES) {
        if (gw < 6144) {
            int f = gw & (FEAT - 1);
            int chunk = gw >> 7;
            int q = chunk * 64 + lane;
            wave_agg_add(true, cluster[q], y[q * FEAT + f], Xnew, FEAT, f);
        } else {
            int q = gw - 6144;
            int cnt = pcnt[q]; if (cnt > PSTRIDE) cnt = PSTRIDE;
            unsigned long long m = qmask[q];
            bool valid = (lane < cnt) && ((m >> lane) & 1ull);
            int p = 0;
            if (valid) p = (int)(ptab[(size_t)q * PSTRIDE + lane] & 0xFFFFFFFFu);
            int cq = cluster[q];
            int cp = valid ? cluster[p] : 0;
            valid = valid && (cp != cq);
            wave_agg_add(valid, cp * N + cq, 1.0f, Anew, 1, 0);
        }
    }
}

extern "C" void kernel_launch(void* const* d_in, const int* in_sizes, int n_in,
                              void* d_out, int out_size, void* d_ws, size_t ws_size,
                              hipStream_t stream) {
    const float* x  = (const float*)d_in[0];
    const int*   ei = (const int*)d_in[1];
    const float* w  = (const float*)d_in[3];
    const float* bb = (const float*)d_in[4];

    // workspace layout: ctrl first (memset), then [pcnt|notsing] (in-kernel zero)
    char* ws = (char*)d_ws;
    size_t off = 0;
    int* ctrl     = (int*)(ws + off);      off += 16;
    int* pcnt     = (int*)(ws + off);      off += (size_t)N * 4;
    int* notsing  = (int*)(ws + off);      off += (size_t)N * 4;
    float* a      = (float*)(ws + off);    off += (size_t)N * 4;
    float* c      = (float*)(ws + off);    off += (size_t)N * 4;
    int* cluster  = (int*)(ws + off);      off += (size_t)N * 4;
    unsigned* ep  = (unsigned*)(ws + off); off += (size_t)NE * 4;
    unsigned long long* qmask = (unsigned long long*)(ws + off); off += (size_t)N * 8;
    float* y      = (float*)(ws + off);    off += (size_t)N * FEAT * 4;
    unsigned long long* ptab = (unsigned long long*)(ws + off); off += (size_t)N * PSTRIDE * 8;

    // output layout (all float32)
    float* Xnew        = (float*)d_out;                 // N*FEAT
    float* Anew        = Xnew + (size_t)N * FEAT;       // N*N
    float* out_cluster = Anew + (size_t)N * N + N;      // after new_batch (zeros)

    hipMemsetAsync(ctrl, 0, 16, stream);
    k_initez<<<DOTB + EDGB + OZB, 256, 0, stream>>>(x, w, ei, bb, a, c, ep, notsing,
                                                    pcnt, ptab, (float4*)d_out,
                                                    (float4*)pcnt, ctrl);
    k_pgr<<<K2B, 1024, 0, stream>>>(ep, x, pcnt, ptab, notsing, y, qmask, cluster,
                                    out_cluster, Xnew, Anew, ctrl);
}

// Round 10
// 133.956 us; speedup vs baseline: 2.1242x; 2.1242x over previous
//
#include <hip/hip_runtime.h>
#include <math.h>

#define N 3072
#define FEAT 128
#define NE 24576
#define PSTRIDE 64         // per-node pair-slot row stride
#define DOTB 768           // k_init dot blocks (4 nodes each)
#define OUTZ4 2458368      // f4 count of [Xnew|Anew|new_batch]
#define ZB3 608            // zero blocks in k_prop_gather (4096 f4 each)
#define GATB 192           // gather blocks (16 q rows each)
#define RESCAP 4096        // residual-edge LDS capacity

// Wave-aggregated atomic add: one atomicAdd per distinct key per wave.
// All 64 lanes must reach this call (use `valid`, not early-return).
__device__ __forceinline__ void wave_agg_add(bool valid, int key, float val,
                                             float* base, int stride, int off) {
    int lane = threadIdx.x & 63;
    unsigned long long active = __ballot(valid ? 1 : 0);
    while (active) {
        int leader = __ffsll(active) - 1;
        int lkey = __shfl(key, leader);
        bool mine = valid && (key == lkey);
        unsigned long long grp = __ballot(mine ? 1 : 0);
        float v = mine ? val : 0.0f;
        #pragma unroll
        for (int o = 32; o; o >>= 1) v += __shfl_xor(v, o);
        if (lane == leader)
            atomicAdd(&base[(size_t)lkey * stride + off], v);
        active &= ~grp;
    }
}

// blocks [0,DOTB): a[i]=x[i].w[0:128], c[i]=x[i].w[128:256] (wave per node)
// block DOTB: zero [pcnt|notsing] (1536 f4)
__global__ void k_init(const float* __restrict__ x, const float* __restrict__ w,
                       float* __restrict__ a, float* __restrict__ c,
                       float4* __restrict__ zws) {
    int b = blockIdx.x, t = threadIdx.x;
    if (b < DOTB) {
        int node = b * 4 + (t >> 6);
        int lane = t & 63;
        const float* xi = x + node * FEAT;
        float pa = xi[lane] * w[lane] + xi[lane + 64] * w[lane + 64];
        float pc = xi[lane] * w[FEAT + lane] + xi[lane + 64] * w[FEAT + lane + 64];
        for (int off = 32; off; off >>= 1) {
            pa += __shfl_down(pa, off);
            pc += __shfl_down(pc, off);
        }
        if (lane == 0) { a[node] = pa; c[node] = pc; }
    } else {
        float4 z = {0.f, 0.f, 0.f, 0.f};
        #pragma unroll
        for (int k = 0; k < 6; ++k) zws[k * 256 + t] = z;
    }
}

// score both directions, pack ep (u|v<<12|fu<<24|fv<<25), mark not-single,
// append (e,p) to q's gather row (dup pairs deduped at gather).
__global__ void k_edge_pairs(const int* __restrict__ ei, const float* __restrict__ a,
                             const float* __restrict__ c, const float* __restrict__ bb,
                             unsigned* __restrict__ ep, int* __restrict__ notsingle,
                             int* __restrict__ pcnt, unsigned long long* __restrict__ ptab) {
    int t = blockIdx.x * blockDim.x + threadIdx.x;
    if (t >= NE) return;
    int u = ei[t], v = ei[NE + t];
    unsigned wpk = (unsigned)u | ((unsigned)v << 12);
    if (u != v) {
        float b = bb[0];
        float su = a[u] + c[v] + b;    // S[u,v]; A_c[u,v]  (edge u->v)
        float sv = a[v] + c[u] + b;    // S[v,u]; A_c[v,u]  (edge v->u)
        unsigned fu = (su > 0.f) ? 1u : 0u;
        unsigned fv = (sv > 0.f) ? 1u : 0u;
        wpk |= (fu << 24) | (fv << 25);
        if (fu | fv) { notsingle[u] = 1; notsingle[v] = 1; }
        float eu = tanhf(su);
        int sl = atomicAdd(&pcnt[v], 1);
        if (sl < PSTRIDE)
            ptab[(size_t)v * PSTRIDE + sl] =
                ((unsigned long long)__float_as_uint(eu) << 32) | (unsigned)u;
        float ev2 = tanhf(sv);
        sl = atomicAdd(&pcnt[u], 1);
        if (sl < PSTRIDE)
            ptab[(size_t)u * PSTRIDE + sl] =
                ((unsigned long long)__float_as_uint(ev2) << 32) | (unsigned)v;
    }
    ep[t] = wpk;
}

// block 0: reach-to-0 bitmap sweeps + residual fixpoint + rank + cluster.
// blocks 1..GATB: dedup + gather y rows. blocks GATB+1..: zero [Xnew|Anew|batch].
__global__ void __launch_bounds__(1024)
k_prop_gather(const unsigned* __restrict__ ep, const float* __restrict__ x,
              const int* __restrict__ pcnt, const unsigned long long* __restrict__ ptab,
              const int* __restrict__ notsingle, float* __restrict__ y,
              unsigned long long* __restrict__ qmask, int* __restrict__ cluster,
              float* __restrict__ out_cluster, float4* __restrict__ zout) {
    __shared__ int lab[N];
    __shared__ unsigned Vw[N / 32];          // reach-to-0 bitmap
    __shared__ unsigned res[RESCAP];         // residual directed edges (p | q<<12)
    __shared__ unsigned short rnodes[N];     // residual node list
    __shared__ int ssum[1024];
    __shared__ unsigned short rk[N];
    __shared__ int sh_p[16 * 64];
    __shared__ int flag, rescnt, rncnt;
    int t = threadIdx.x, blk = blockIdx.x;
    int wv = t >> 6, lane = t & 63;
    if (blk == 0) {
        if (t < N / 32) Vw[t] = (t == 0) ? 1u : 0u;
        if (t == 0) { rescnt = 0; rncnt = 0; }
        unsigned act = 0x00FFFFFFu;          // 24 edges per thread, strided
        // ---- V sweeps: u joins V if (u->v flagged) && v in V ----
        for (;;) {
            __syncthreads();
            if (t == 0) flag = 0;
            __syncthreads();
            unsigned rem = act;
            while (rem) {
                int j = __ffs(rem) - 1;
                rem &= rem - 1;
                unsigned wpk = ep[t + j * 1024];
                if (!(wpk & 0x3000000u)) { act &= ~(1u << j); continue; }
                int u = wpk & 0xFFF, v = (wpk >> 12) & 0xFFF;
                unsigned pu = (Vw[u >> 5] >> (u & 31)) & 1u;
                unsigned pv = (Vw[v >> 5] >> (v & 31)) & 1u;
                if ((wpk & (1u << 24)) && pv && !pu) {
                    atomicOr(&Vw[u >> 5], 1u << (u & 31)); pu = 1; flag = 1;
                }
                if ((wpk & (1u << 25)) && pu && !pv) {
                    atomicOr(&Vw[v >> 5], 1u << (v & 31)); pv = 1; flag = 1;
                }
                bool done = (pu || !(wpk & (1u << 24))) && (pv || !(wpk & (1u << 25)));
                if (done) act &= ~(1u << j);
            }
            __syncthreads();
            if (!flag) break;
        }
        // ---- compact residue (sources not in V); residue is closed ----
        unsigned rem = act;
        while (rem) {
            int j = __ffs(rem) - 1;
            rem &= rem - 1;
            unsigned wpk = ep[t + j * 1024];
            int u = wpk & 0xFFF, v = (wpk >> 12) & 0xFFF;
            unsigned pu = (Vw[u >> 5] >> (u & 31)) & 1u;
            unsigned pv = (Vw[v >> 5] >> (v & 31)) & 1u;
            if ((wpk & (1u << 24)) && !pu) {     // lab[u] <- lab[v]
                int pos = atomicAdd(&rescnt, 1);
                if (pos < RESCAP) res[pos] = (unsigned)u | ((unsigned)v << 12);
            }
            if ((wpk & (1u << 25)) && !pv) {     // lab[v] <- lab[u]
                int pos = atomicAdd(&rescnt, 1);
                if (pos < RESCAP) res[pos] = (unsigned)v | ((unsigned)u << 12);
            }
        }
        // labels: V nodes -> 0 (0 is global min and reachable); others identity
        for (int i = t; i < N; i += 1024) {
            unsigned inV = (Vw[i >> 5] >> (i & 31)) & 1u;
            lab[i] = inV ? 0 : i;
            if (!inV) {
                int pos = atomicAdd(&rncnt, 1);
                rnodes[pos] = (unsigned short)i;
            }
        }
        __syncthreads();
        int nres = rescnt < RESCAP ? rescnt : RESCAP;
        bool ovf = (rescnt > RESCAP);
        int nrn = rncnt;
        // ---- residual fixpoint (tiny; fallback to full edges on overflow) ----
        for (;;) {
            __syncthreads();
            if (t == 0) flag = 0;
            __syncthreads();
            if (!ovf) {
                for (int k = t; k < nres; k += 1024) {
                    unsigned w2 = res[k];
                    int p = w2 & 0xFFF, q = (w2 >> 12) & 0xFFF;
                    int lq = lab[q];
                    if (lq < lab[p]) { atomicMin(&lab[p], lq); flag = 1; }
                }
                for (int k = t; k < nrn; k += 1024) {
                    int i = rnodes[k];
                    int m = lab[i];
                    int mm = lab[m];
                    while (mm < m) { m = mm; mm = lab[m]; }
                    if (m < lab[i]) { atomicMin(&lab[i], m); flag = 1; }
                }
            } else {
                for (int j = 0; j < 24; ++j) {
                    unsigned wpk = ep[t + j * 1024];
                    int u = wpk & 0xFFF, v = (wpk >> 12) & 0xFFF;
                    if (wpk & (1u << 24)) {
                        int lv = lab[v];
                        if (lv < lab[u]) { atomicMin(&lab[u], lv); flag = 1; }
                    }
                    if (wpk & (1u << 25)) {
                        int lu = lab[u];
                        if (lu < lab[v]) { atomicMin(&lab[v], lu); flag = 1; }
                    }
                }
                for (int i = t; i < N; i += 1024) {
                    int m = lab[i];
                    if (m == 0) continue;
                    int mm = lab[m];
                    while (mm < m) { m = mm; mm = lab[m]; }
                    if (m < lab[i]) { atomicMin(&lab[i], m); flag = 1; }
                }
            }
            __syncthreads();
            if (!flag) break;
        }
        // ---- rank roots: cumsum(lab[i]==i)-1; cluster[j]=rank[lab[j]] ----
        int i0 = 3 * t;
        int r0 = (lab[i0] == i0);
        int r1 = (lab[i0 + 1] == i0 + 1);
        int r2 = (lab[i0 + 2] == i0 + 2);
        int s = r0 + r1 + r2;
        ssum[t] = s;
        __syncthreads();
        for (int off = 1; off < 1024; off <<= 1) {
            int val = (t >= off) ? ssum[t - off] : 0;
            __syncthreads();
            ssum[t] += val;
            __syncthreads();
        }
        int run = ssum[t] - s;
        run += r0; rk[i0]     = (unsigned short)(run - 1);
        run += r1; rk[i0 + 1] = (unsigned short)(run - 1);
        run += r2; rk[i0 + 2] = (unsigned short)(run - 1);
        __syncthreads();
        for (int j = t; j < N; j += 1024) {
            int cl = rk[lab[j]];
            cluster[j] = cl;
            out_cluster[j] = (float)cl;
        }
    } else if (blk <= GATB) {
        int q = (blk - 1) * 16 + wv;
        int cnt = pcnt[q]; if (cnt > PSTRIDE) cnt = PSTRIDE;
        const unsigned long long* row = ptab + (size_t)q * PSTRIDE;
        int myp = -1 - lane;      // unique negative: never matches a real p
        float mye = 0.f;
        if (lane < cnt) {
            unsigned long long s = row[lane];
            myp = (int)(s & 0xFFFFFFFFu);
            mye = __uint_as_float((unsigned)(s >> 32));
        }
        sh_p[wv * 64 + lane] = myp;
        bool dup = false;
        for (int j = 0; j < lane && !dup; ++j)
            dup = (sh_p[wv * 64 + j] == myp);
        bool valid = (lane < cnt) && !dup;
        unsigned long long m = __ballot(valid ? 1 : 0);
        if (lane == 0) qmask[q] = m;
        float acc0 = 0.f, acc1 = 0.f;
        for (int j = 0; j < cnt; ++j) {
            if (!((m >> j) & 1ull)) continue;
            int p = __shfl(myp, j);
            float e = __shfl(mye, j);
            const float* xp = x + p * FEAT;
            acc0 += e * xp[lane];
            acc1 += e * xp[lane + 64];
        }
        if (!notsingle[q]) {
            const float* xq = x + q * FEAT;
            acc0 += xq[lane];
            acc1 += xq[lane + 64];
        }
        float* yq = y + q * FEAT;
        yq[lane] = acc0;
        yq[lane + 64] = acc1;
    } else {
        float4 z = {0.f, 0.f, 0.f, 0.f};
        int base = (blk - GATB - 1) * 4096;
        #pragma unroll
        for (int k = 0; k < 4; ++k) {
            int idx = base + k * 1024 + t;
            if (idx < OUTZ4) zout[idx] = z;
        }
    }
}

// gwaves [0,6144): X_new[cluster[q]][f] += y[q][f] (wave-aggregated)
// gwaves [6144,9216): A_new counts from ptab/qmask, diagonal keys skipped
__global__ void k_reduce_anew(const float* __restrict__ y, const int* __restrict__ cluster,
                              const int* __restrict__ pcnt,
                              const unsigned long long* __restrict__ ptab,
                              const unsigned long long* __restrict__ qmask,
                              float* __restrict__ Xnew, float* __restrict__ Anew) {
    int gid = blockIdx.x * blockDim.x + threadIdx.x;
    int wid = gid >> 6, lane = gid & 63;
    if (wid < 6144) {
        int f = wid & (FEAT - 1);
        int chunk = wid >> 7;
        int q = chunk * 64 + lane;
        wave_agg_add(true, cluster[q], y[q * FEAT + f], Xnew, FEAT, f);
    } else {
        int q = wid - 6144;
        int cnt = pcnt[q]; if (cnt > PSTRIDE) cnt = PSTRIDE;
        unsigned long long m = qmask[q];
        bool valid = (lane < cnt) && ((m >> lane) & 1ull);
        int p = 0;
        if (valid) p = (int)(ptab[(size_t)q * PSTRIDE + lane] & 0xFFFFFFFFu);
        int cq = cluster[q];
        int cp = valid ? cluster[p] : 0;
        valid = valid && (cp != cq);
        wave_agg_add(valid, cp * N + cq, 1.0f, Anew, 1, 0);
    }
}

extern "C" void kernel_launch(void* const* d_in, const int* in_sizes, int n_in,
                              void* d_out, int out_size, void* d_ws, size_t ws_size,
                              hipStream_t stream) {
    const float* x  = (const float*)d_in[0];
    const int*   ei = (const int*)d_in[1];
    const float* w  = (const float*)d_in[3];
    const float* bb = (const float*)d_in[4];

    // workspace layout — zero region FIRST: [pcnt | notsing] (24,576 B)
    char* ws = (char*)d_ws;
    size_t off = 0;
    int* pcnt     = (int*)(ws + off);      off += (size_t)N * 4;
    int* notsing  = (int*)(ws + off);      off += (size_t)N * 4;
    float* a      = (float*)(ws + off);    off += (size_t)N * 4;
    float* c      = (float*)(ws + off);    off += (size_t)N * 4;
    int* cluster  = (int*)(ws + off);      off += (size_t)N * 4;
    unsigned* ep  = (unsigned*)(ws + off); off += (size_t)NE * 4;
    unsigned long long* qmask = (unsigned long long*)(ws + off); off += (size_t)N * 8;
    float* y      = (float*)(ws + off);    off += (size_t)N * FEAT * 4;
    unsigned long long* ptab = (unsigned long long*)(ws + off); off += (size_t)N * PSTRIDE * 8;

    // output layout (all float32)
    float* Xnew        = (float*)d_out;                 // N*FEAT
    float* Anew        = Xnew + (size_t)N * FEAT;       // N*N
    float* out_cluster = Anew + (size_t)N * N + N;      // after new_batch (zeros)

    k_init<<<DOTB + 1, 256, 0, stream>>>(x, w, a, c, (float4*)pcnt);
    k_edge_pairs<<<NE / 256, 256, 0, stream>>>(ei, a, c, bb, ep, notsing, pcnt, ptab);
    k_prop_gather<<<1 + GATB + ZB3, 1024, 0, stream>>>(ep, x, pcnt, ptab, notsing, y,
                                                       qmask, cluster, out_cluster,
                                                       (float4*)d_out);
    k_reduce_anew<<<(9216 * 64) / 1024, 1024, 0, stream>>>(y, cluster, pcnt, ptab,
                                                           qmask, Xnew, Anew);
}